// Round 1
// baseline (2144.484 us; speedup 1.0000x reference)
//
#include <hip/hip_runtime.h>
#include <hip/hip_bf16.h>

typedef float f32x4 __attribute__((ext_vector_type(4)));
typedef __bf16 bf16x8 __attribute__((ext_vector_type(8)));

#define DEV __device__ __forceinline__

namespace {

constexpr int PIXP = 912;   // padded pixels (57 tiles of 16)
constexpr int NT   = 57;    // pixel tiles
constexpr int XS   = 40;    // x_lds row stride (elems): 80B, 16B-aligned, 2-way bank phase
constexpr int YS   = 24;    // Y_buf row stride: 48B
constexpr int CS   = 40;    // x1c/x2t row stride: 80B

constexpr int E_XS = PIXP * XS;        // 36480
constexpr int E_MS = PIXP;             // 912
constexpr int E_M0 = PIXP;             // 912
constexpr int E_Y  = PIXP * YS;        // 21888
constexpr int E_C  = 8 * 32 * CS;      // 10240
constexpr int BF16_ELEMS = E_XS + E_MS + E_M0 + E_Y + 2 * E_C;   // 80672
constexpr int SMEM_BYTES = BF16_ELEMS * 2 + 400 * 4;             // 162944 <= 163840

DEV f32x4 mfma16(bf16x8 a, bf16x8 b, f32x4 c) {
    return __builtin_amdgcn_mfma_f32_16x16x32_bf16(a, b, c, 0, 0, 0);
}

DEV bf16x8 load8(const __bf16* p) {   // 16B-aligned by construction -> ds_read_b128
    return *(const bf16x8*)p;
}

} // namespace

// One workgroup per batch element. 8 waves.
// LDS map: xs[912][40] (x, pixel-major, ch 40..: zero) | Ms[912] | M0[912] |
//          Yb[912][24] (16 k-slots + zero pad) | x1c[8][32][40] ([c][i][k]) |
//          x2t[8][32][40] ([c][j][k] = X2^T) | xo[5][2][40] f32 feature sums.
// All K padding is enforced on the WEIGHT side (predicated->0 in registers);
// LDS is zero-initialized once so out-of-range bf16 reads are always finite.
__global__ __launch_bounds__(512, 2) void ppgn_fused(
    const float* __restrict__ X2g, const float* __restrict__ Mg,
    const float* __restrict__ w11, const float* __restrict__ w12,
    const float* __restrict__ w13, const float* __restrict__ wAg,
    const float* __restrict__ wBg, const float* __restrict__ wCg,
    const float* __restrict__ h1w, const float* __restrict__ h1b,
    float* __restrict__ out)
{
    extern __shared__ char smem[];
    __bf16* xs  = (__bf16*)smem;
    __bf16* MsL = xs + E_XS;
    __bf16* M0L = MsL + E_MS;
    __bf16* Yb  = M0L + E_M0;
    __bf16* x1c = Yb + E_Y;
    __bf16* x2t = x1c + E_C;
    float*  xo  = (float*)(x2t + E_C);

    const int tid  = threadIdx.x;
    const int wv   = tid >> 6;     // wave 0..7
    const int lane = tid & 63;
    const int lq   = lane & 15;    // fragment col/row selector
    const int lh   = lane >> 4;    // k-group 0..3
    const int b    = blockIdx.x;

    // ---- zero all LDS ----
    {
        unsigned int* p = (unsigned int*)smem;
        for (int i = tid; i < SMEM_BYTES / 4; i += 512) p[i] = 0u;
    }
    __syncthreads();

    // ---- stage inputs: x (3 ch) and masks ----
    {
        const float* xb = X2g + b * 2700;
        for (int idx = tid; idx < 2700; idx += 512) {
            int c  = idx / 900;
            int px = idx - c * 900;
            xs[px * XS + c] = (__bf16)xb[idx];
        }
        const float* mb = Mg + b * 1800;
        for (int px = tid; px < 900; px += 512) {
            float m0 = mb[px], m1 = mb[900 + px];
            MsL[px] = (__bf16)(m0 + m1);
            M0L[px] = (__bf16)m0;
        }
    }
    __syncthreads();

    for (int itb = 0; itb < 5; ++itb) {
        const float *wa, *wb, *wc;
        int kAB, sAB, kX, sC;
        if (itb == 0) { wa = w11; wb = w12; kAB = 3;  sAB = 3;  wc = w13; kX = 3;  sC = 43; }
        else {
            wa = wAg + (itb - 1) * 1600; wb = wBg + (itb - 1) * 1600; kAB = 40; sAB = 40;
            wc = wCg + (itb - 1) * 3200; kX = 40; sC = 80;
        }
        const bool two = (kAB > 32);

        // persistent xn accumulators: tile it (nt = wv + 8*it), Mtile m (o = 16m..)
        f32x4 acc[8][3];
        #pragma unroll
        for (int i = 0; i < 8; ++i) {
            #pragma unroll
            for (int m = 0; m < 3; ++m) acc[i][m] = f32x4{0.f, 0.f, 0.f, 0.f};
        }

        for (int cp = 0; cp < 3; ++cp) {           // chunk pairs {0,1},{2,3},{4}
            const int nch = (cp < 2) ? 2 : 1;
            for (int hc = 0; hc < nch; ++hc) {
                const int chunk = cp * 2 + hc;
                const int c0 = chunk * 8;
                // ---- Op1: x1/x2 conv for 8 channels (rows 0..7 = x1, 8..15 = x2) ----
                {
                    const float* rowp = ((lq < 8) ? wa : wb) + (c0 + (lq & 7)) * sAB;
                    bf16x8 af0, af1;
                    #pragma unroll
                    for (int e = 0; e < 8; ++e) {
                        const int k = 8 * lh + e;
                        af0[e] = (__bf16)((k < kAB) ? rowp[k] : 0.f);
                    }
                    if (two) {
                        #pragma unroll
                        for (int e = 0; e < 8; ++e) {
                            const int k = 32 + 8 * lh + e;
                            af1[e] = (__bf16)((k < kAB) ? rowp[k] : 0.f);
                        }
                    }
                    #pragma unroll
                    for (int it = 0; it < 8; ++it) {
                        const int nt = wv + 8 * it;
                        if (nt < NT) {
                            const int px = nt * 16 + lq;
                            const __bf16* bp = xs + px * XS + 8 * lh;
                            f32x4 a4 = f32x4{0.f, 0.f, 0.f, 0.f};
                            a4 = mfma16(af0, load8(bp), a4);
                            if (two) a4 = mfma16(af1, load8(bp + 32), a4);
                            if (px < 900) {
                                const float ms = (float)MsL[px];
                                const int i30 = px / 30;
                                const int j30 = px - i30 * 30;
                                #pragma unroll
                                for (int r = 0; r < 4; ++r) {
                                    const int o = 4 * lh + r;
                                    const __bf16 hv = (__bf16)fmaxf(a4[r] * ms, 0.f);
                                    if (o < 8) x1c[(o * 32 + i30) * CS + j30] = hv;       // [c][i][k=j]
                                    else       x2t[((o - 8) * 32 + j30) * CS + i30] = hv; // [c][j][k=i]
                                }
                            }
                        }
                    }
                }
                __syncthreads();
                // ---- Op2: per-channel 30x30 spatial matmul (one channel per wave) ----
                {
                    const __bf16* ab = x1c + wv * 32 * CS;
                    const __bf16* bb = x2t + wv * 32 * CS;
                    bf16x8 aA[2], bB[2];
                    #pragma unroll
                    for (int m = 0; m < 2; ++m) aA[m] = load8(ab + (m * 16 + lq) * CS + 8 * lh);
                    #pragma unroll
                    for (int n = 0; n < 2; ++n) bB[n] = load8(bb + (n * 16 + lq) * CS + 8 * lh);
                    const int slot = 8 * (chunk & 1) + wv;
                    #pragma unroll
                    for (int m = 0; m < 2; ++m) {
                        #pragma unroll
                        for (int n = 0; n < 2; ++n) {
                            f32x4 ay = f32x4{0.f, 0.f, 0.f, 0.f};
                            ay = mfma16(aA[m], bB[n], ay);
                            #pragma unroll
                            for (int r = 0; r < 4; ++r) {
                                const int i = m * 16 + 4 * lh + r;
                                const int j = n * 16 + lq;
                                if (i < 30 && j < 30) {
                                    const int px = i * 30 + j;
                                    Yb[px * YS + slot] = (__bf16)(ay[r] * (float)MsL[px]);
                                }
                            }
                        }
                    }
                }
                __syncthreads();
            }
            // ---- Op3 partial: xn += wc[:, cp*16 .. cp*16+16) @ Y(16 slots) ----
            {
                bf16x8 yf[3];
                #pragma unroll
                for (int m = 0; m < 3; ++m) {
                    const int o = m * 16 + lq;
                    #pragma unroll
                    for (int e = 0; e < 8; ++e) {
                        const int kl = 8 * lh + e;           // 0..31; slots >=16 are zero-weight
                        const int kg = cp * 16 + kl;
                        yf[m][e] = (__bf16)((o < 40 && kl < 16 && kg < 40) ? wc[o * sC + kg] : 0.f);
                    }
                }
                #pragma unroll
                for (int it = 0; it < 8; ++it) {
                    const int nt = wv + 8 * it;
                    if (nt < NT) {
                        const bf16x8 bf = load8(Yb + (nt * 16 + lq) * YS + 8 * lh);
                        #pragma unroll
                        for (int m = 0; m < 3; ++m) acc[it][m] = mfma16(yf[m], bf, acc[it][m]);
                    }
                }
            }
            __syncthreads();
        }
        // ---- Op3 x-part: xn += wc[:, 40:40+kX) @ x ----
        {
            bf16x8 xf0[3], xf1[3];
            #pragma unroll
            for (int m = 0; m < 3; ++m) {
                const int o = m * 16 + lq;
                #pragma unroll
                for (int e = 0; e < 8; ++e) {
                    const int k = 8 * lh + e;
                    xf0[m][e] = (__bf16)((o < 40 && k < kX) ? wc[o * sC + 40 + k] : 0.f);
                }
            }
            const bool twoX = (kX > 32);
            if (twoX) {
                #pragma unroll
                for (int m = 0; m < 3; ++m) {
                    const int o = m * 16 + lq;
                    #pragma unroll
                    for (int e = 0; e < 8; ++e) {
                        const int k = 32 + 8 * lh + e;
                        xf1[m][e] = (__bf16)((o < 40 && k < kX) ? wc[o * sC + 40 + k] : 0.f);
                    }
                }
            }
            #pragma unroll
            for (int it = 0; it < 8; ++it) {
                const int nt = wv + 8 * it;
                if (nt < NT) {
                    const __bf16* bp = xs + (nt * 16 + lq) * XS + 8 * lh;
                    const bf16x8 b0 = load8(bp);
                    #pragma unroll
                    for (int m = 0; m < 3; ++m) acc[it][m] = mfma16(xf0[m], b0, acc[it][m]);
                    if (twoX) {
                        const bf16x8 b1 = load8(bp + 32);
                        #pragma unroll
                        for (int m = 0; m < 3; ++m) acc[it][m] = mfma16(xf1[m], b1, acc[it][m]);
                    }
                }
            }
        }
        __syncthreads();   // all x reads complete before overwrite
        // ---- epilogue: xn = relu(acc*Ms); xo sums (fp32, pre-rounding); write new x ----
        {
            float xoA[3][4], xoB[3][4];
            #pragma unroll
            for (int m = 0; m < 3; ++m) {
                #pragma unroll
                for (int r = 0; r < 4; ++r) { xoA[m][r] = 0.f; xoB[m][r] = 0.f; }
            }
            #pragma unroll
            for (int it = 0; it < 8; ++it) {
                const int nt = wv + 8 * it;
                if (nt < NT) {
                    const int px = nt * 16 + lq;
                    if (px < 900) {
                        const float ms = (float)MsL[px];
                        const float m0 = (float)M0L[px];
                        const float m1 = ms - m0;
                        #pragma unroll
                        for (int m = 0; m < 3; ++m) {
                            #pragma unroll
                            for (int r = 0; r < 4; ++r) {
                                const int o = m * 16 + 4 * lh + r;
                                if (o < 40) {
                                    const float v = fmaxf(acc[it][m][r] * ms, 0.f);
                                    xoA[m][r] += v * m0;
                                    xoB[m][r] += v * m1;
                                    xs[px * XS + o] = (__bf16)v;
                                }
                            }
                        }
                    }
                }
            }
            #pragma unroll
            for (int m = 0; m < 3; ++m) {
                #pragma unroll
                for (int r = 0; r < 4; ++r) {
                    float a = xoA[m][r], b2 = xoB[m][r];
                    #pragma unroll
                    for (int d = 1; d < 16; d <<= 1) {
                        a  += __shfl_xor(a, d, 64);
                        b2 += __shfl_xor(b2, d, 64);
                    }
                    const int o = m * 16 + 4 * lh + r;
                    if (lq == 0 && o < 40) {
                        atomicAdd(&xo[itb * 80 + o], a);
                        atomicAdd(&xo[itb * 80 + 40 + o], b2);
                    }
                }
            }
        }
        __syncthreads();
    }

    // ---- head: out = relu(feat @ h1w^T + h1b), feat = xo[400] ----
    {
        const int hh = wv * 4 + lh;   // 0..31
        float s = 0.f;
        #pragma unroll
        for (int k2 = 0; k2 < 25; ++k2) {
            const int f = lq + 16 * k2;
            s += xo[f] * h1w[hh * 400 + f];
        }
        #pragma unroll
        for (int d = 1; d < 16; d <<= 1) s += __shfl_xor(s, d, 64);
        if (lq == 0) out[b * 32 + hh] = fmaxf(s + h1b[hh], 0.f);
    }
}

extern "C" void kernel_launch(void* const* d_in, const int* in_sizes, int n_in,
                              void* d_out, int out_size, void* d_ws, size_t ws_size,
                              hipStream_t stream) {
    (void)in_sizes; (void)n_in; (void)d_ws; (void)ws_size; (void)out_size;
    const float* X2  = (const float*)d_in[0];
    const float* M   = (const float*)d_in[1];
    const float* w11 = (const float*)d_in[2];
    const float* w12 = (const float*)d_in[3];
    const float* w13 = (const float*)d_in[4];
    const float* wA  = (const float*)d_in[5];
    const float* wB  = (const float*)d_in[6];
    const float* wC  = (const float*)d_in[7];
    const float* h1w = (const float*)d_in[8];
    const float* h1b = (const float*)d_in[9];
    float* out = (float*)d_out;

    (void)hipFuncSetAttribute(reinterpret_cast<const void*>(ppgn_fused),
                              hipFuncAttributeMaxDynamicSharedMemorySize, SMEM_BYTES);
    ppgn_fused<<<2048, 512, SMEM_BYTES, stream>>>(X2, M, w11, w12, w13,
                                                  wA, wB, wC, h1w, h1b, out);
}